// Round 8
// baseline (347.517 us; speedup 1.0000x reference)
//
#include <hip/hip_runtime.h>

constexpr int N_NODES = 50000;
constexpr int IN_C    = 128;
constexpr int HID_C   = 128;
constexpr int OUT_C   = 64;
constexpr int N_EDGES = 800000;
constexpr int N_LABEL = 200000;
constexpr float BN_EPS = 1e-5f;
constexpr int NCHUNK  = (N_NODES + 256) / 256 + 1;   // 196 chunks cover 50176 >= 50001

typedef __attribute__((ext_vector_type(8))) short bf16x8;
typedef __attribute__((ext_vector_type(4))) float f32x4;

// ---- bf16 helpers (plain ushort storage) ----------------------------------
__device__ __forceinline__ float bf_lo(unsigned v) {
    union { unsigned u; float f; } t; t.u = v << 16; return t.f;
}
__device__ __forceinline__ float bf_hi(unsigned v) {
    union { unsigned u; float f; } t; t.u = v & 0xffff0000u; return t.f;
}
__device__ __forceinline__ float bf1(unsigned short u) {
    union { unsigned u; float f; } t; t.u = ((unsigned)u) << 16; return t.f;
}
__device__ __forceinline__ unsigned short f2bf(float f) {
    union { float f; unsigned u; } t; t.f = f;
    unsigned r = t.u + 0x7fffu + ((t.u >> 16) & 1u);   // round-nearest-even
    return (unsigned short)(r >> 16);
}

// ---------------------------------------------------------------------------
// CSR build step 1: histogram of dst; also record each edge's rank within its
// destination node (atomicAdd return value) -> scatter needs no atomics.
__global__ void hist_kernel(const int* __restrict__ dst, int* __restrict__ deg,
                            int* __restrict__ rank) {
    int e = blockIdx.x * blockDim.x + threadIdx.x;
    if (e < N_EDGES) rank[e] = atomicAdd(&deg[dst[e]], 1);
}

// CSR build step 2a: per-chunk sums (deg is zero-padded past N_NODES)
__global__ void chunk_sum_kernel(const int* __restrict__ deg, int* __restrict__ bsum) {
    int i = blockIdx.x * 256 + threadIdx.x;
    int v = deg[i];
    #pragma unroll
    for (int o = 32; o > 0; o >>= 1) v += __shfl_down(v, o, 64);
    __shared__ int ws[4];
    if ((threadIdx.x & 63) == 0) ws[threadIdx.x >> 6] = v;
    __syncthreads();
    if (threadIdx.x == 0) bsum[blockIdx.x] = ws[0] + ws[1] + ws[2] + ws[3];
}

// CSR build step 2b: exclusive scan of the chunk sums (single tiny block)
__global__ void scan_bsum_kernel(const int* __restrict__ bsum, int* __restrict__ boff) {
    __shared__ int t[256];
    int tid = threadIdx.x;
    t[tid] = (tid < NCHUNK) ? bsum[tid] : 0;
    __syncthreads();
    for (int o = 1; o < 256; o <<= 1) {
        int v = t[tid];
        int add = (tid >= o) ? t[tid - o] : 0;
        __syncthreads();
        t[tid] = v + add;
        __syncthreads();
    }
    boff[tid] = (tid == 0) ? 0 : t[tid - 1];
}

// CSR build step 2c: per-chunk exclusive scan + chunk offset -> off
__global__ void scan_final_kernel(const int* __restrict__ deg, const int* __restrict__ boff,
                                  int* __restrict__ off) {
    __shared__ int t[256];
    int tid = threadIdx.x;
    int i = blockIdx.x * 256 + tid;
    int d = deg[i];
    t[tid] = d;
    __syncthreads();
    for (int o = 1; o < 256; o <<= 1) {
        int v = t[tid];
        int add = (tid >= o) ? t[tid - o] : 0;
        __syncthreads();
        t[tid] = v + add;
        __syncthreads();
    }
    int excl = boff[blockIdx.x] + t[tid] - d;
    if (i <= N_NODES) off[i] = excl;       // off[N_NODES] == N_EDGES (deg pad = 0)
}

// CSR build step 3: place src ids (atomic-free: pos = off[dst] + rank)
__global__ void scatter_kernel(const int* __restrict__ src, const int* __restrict__ dst,
                               const int* __restrict__ off, const int* __restrict__ rank,
                               int* __restrict__ csr_src) {
    int e = blockIdx.x * blockDim.x + threadIdx.x;
    if (e < N_EDGES) csr_src[off[dst[e]] + rank[e]] = src[e];
}

// ---------------------------------------------------------------------------
// prep_B: pack [Wl | Wr] (f32, row-major [128][HALF] each) into bf16 fragment
// order for mfma_f32_16x16x32_bf16 B-operand:
//   Bp[((nt*4 + kt)*64 + l)*8 + j] = B[kt*32 + (l>>4)*8 + j][nt*16 + (l&15)]
__global__ void prep_B(const float* __restrict__ Wl, const float* __restrict__ Wr,
                       short* __restrict__ Bp, int C) {
    int f = blockIdx.x * 256 + threadIdx.x;
    if (f >= 128 * C) return;
    int HALF = C >> 1;
    int j = f & 7;
    int l = (f >> 3) & 63;
    int ktnt = f >> 9;
    int kt = ktnt & 3, nt = ktnt >> 2;
    int n = nt * 16 + (l & 15);
    int k = kt * 32 + ((l >> 4) << 3) + j;
    float v = (n < HALF) ? Wl[k * HALF + n] : Wr[k * HALF + (n - HALF)];
    Bp[f] = (short)f2bf(v);
}

// ---------------------------------------------------------------------------
// MFMA GEMM: B pre-packed bf16 in global, staged to LDS as a pure 16B/lane
// memcpy (no conversion VALU, no bank conflicts on write or read).
//   MODE 0 (conv1): A = x (f32), C=256; cols 0..127 -> y1 (bf16),
//                   cols 128..255 -> h = . + b1 (f32)
//   MODE 1 (conv2): A = relu(h*ss0 + ss1) (fused BN), C=128;
//                   cols 0..63 -> t2l (bf16); cols 64..127 -> t2r = . + b2 (bf16)
// Block = 512 threads = 8 waves: 4 row-groups x 2 column-halves; each wave
// computes 16 rows x C/2 cols. Fragment layouts (verified m89/m91):
//   A: lane l, elem j <- A[m0 + (l&15)][kt*32 + (l>>4)*8 + j]
//   B: lane l, elem j <- B[kt*32 + (l>>4)*8 + j][nt*16 + (l&15)]  (packed order)
//   D: lane l, reg  j -> D[m0 + (l>>4)*4 + j][nt*16 + (l&15)]
template <int MODE>
__global__ __launch_bounds__(512) void mfma_gemm(
    const float* __restrict__ A, const short* __restrict__ Bp,
    const float* __restrict__ bias, const float* __restrict__ ss,
    unsigned short* __restrict__ outL,
    float* __restrict__ outHf, unsigned short* __restrict__ outHb)
{
    constexpr int C    = (MODE == 0) ? 256 : 128;
    constexpr int NT   = C / 16;
    constexpr int NTH  = NT / 2;       // column tiles per wave
    constexpr int HALF = C / 2;
    constexpr int CHUNKS = 128 * C / 8;     // 16B chunks (4096 / 2048)

    __shared__ short sB[128 * C];           // 64 KB (MODE0) / 32 KB (MODE1)

    // ---- stage pre-packed B: straight 16B-per-lane copy ----
    {
        const float4* bp4 = reinterpret_cast<const float4*>(Bp);
        float4* sb4 = reinterpret_cast<float4*>(sB);
        #pragma unroll
        for (int i = 0; i < CHUNKS / 512; ++i)
            sb4[i * 512 + threadIdx.x] = bp4[i * 512 + threadIdx.x];
    }

    int tid  = threadIdx.x;
    int wid  = tid >> 6, lane = tid & 63;
    int wr   = wid >> 1, wc = wid & 1;
    int m0   = blockIdx.x * 64 + wr * 16;
    int row  = m0 + (lane & 15);
    int rowc = (row < N_NODES) ? row : (N_NODES - 1);
    const float* ap = A + (long long)rowc * 128;
    int kbase = (lane >> 4) * 8;

    // ---- A fragments (f32 -> bf16, optional fused BN+ReLU) ----
    bf16x8 a[4];
    #pragma unroll
    for (int kt = 0; kt < 4; ++kt) {
        int k0 = kt * 32 + kbase;
        float4 u0 = *reinterpret_cast<const float4*>(ap + k0);
        float4 u1 = *reinterpret_cast<const float4*>(ap + k0 + 4);
        float v[8] = {u0.x, u0.y, u0.z, u0.w, u1.x, u1.y, u1.z, u1.w};
        if (MODE == 1) {
            float4 s0 = *reinterpret_cast<const float4*>(ss + k0);
            float4 s1 = *reinterpret_cast<const float4*>(ss + k0 + 4);
            float4 t0 = *reinterpret_cast<const float4*>(ss + 128 + k0);
            float4 t1 = *reinterpret_cast<const float4*>(ss + 128 + k0 + 4);
            float sc[8] = {s0.x, s0.y, s0.z, s0.w, s1.x, s1.y, s1.z, s1.w};
            float sh[8] = {t0.x, t0.y, t0.z, t0.w, t1.x, t1.y, t1.z, t1.w};
            #pragma unroll
            for (int j = 0; j < 8; ++j) v[j] = fmaxf(v[j] * sc[j] + sh[j], 0.f);
        }
        #pragma unroll
        for (int j = 0; j < 8; ++j) a[kt][j] = (short)f2bf(v[j]);
    }

    __syncthreads();

    // ---- MFMA main loop: B fragments from LDS (conflict-free b128 reads) ----
    f32x4 acc[NTH] = {};
    #pragma unroll 1
    for (int kt = 0; kt < 4; ++kt) {
        #pragma unroll
        for (int t = 0; t < NTH; ++t) {
            int nt = wc * NTH + t;
            bf16x8 b = *reinterpret_cast<const bf16x8*>(
                sB + ((((nt << 2) + kt) * 64 + lane) << 3));
            acc[t] = __builtin_amdgcn_mfma_f32_16x16x32_bf16(a[kt], b, acc[t], 0, 0, 0);
        }
    }

    // ---- epilogue ----
    int r0 = m0 + ((lane >> 4) << 2);
    int nl = lane & 15;
    #pragma unroll
    for (int t = 0; t < NTH; ++t) {
        int col = (wc * NTH + t) * 16 + nl;
        float bb = (col >= HALF) ? bias[col - HALF] : 0.f;
        #pragma unroll
        for (int j = 0; j < 4; ++j) {
            int r = r0 + j;
            if (r >= N_NODES) continue;
            float vv = acc[t][j];
            if (MODE == 0) {
                if (col < HALF) outL[(long long)r * 128 + col] = f2bf(vv);
                else            outHf[(long long)r * 128 + (col - HALF)] = vv + bb;
            } else {
                if (col < HALF) outL[(long long)r * 64 + col] = f2bf(vv);
                else            outHb[(long long)r * 64 + (col - HALF)] = f2bf(vv + bb);
            }
        }
    }
}

// ---------------------------------------------------------------------------
// conv1 aggregate: h[n] += mean_{s in N(n)} y1[s]  (y1 bf16-packed, 128 ch)
__global__ __launch_bounds__(256) void agg_mean_add_128(
    const int* __restrict__ off, const int* __restrict__ csr_src,
    const unsigned* __restrict__ ybf, float* __restrict__ h) {
    int node = blockIdx.x * 4 + (threadIdx.x >> 6);
    if (node >= N_NODES) return;
    int lane = threadIdx.x & 63;
    int beg = off[node], end = off[node + 1];
    float ax = 0.f, ay = 0.f;
    int i = beg;
    for (; i + 3 < end; i += 4) {
        int s0 = csr_src[i];
        int s1 = csr_src[i + 1];
        int s2 = csr_src[i + 2];
        int s3 = csr_src[i + 3];
        unsigned v0 = ybf[(long long)s0 * 64 + lane];
        unsigned v1 = ybf[(long long)s1 * 64 + lane];
        unsigned v2 = ybf[(long long)s2 * 64 + lane];
        unsigned v3 = ybf[(long long)s3 * 64 + lane];
        ax += bf_lo(v0) + bf_lo(v1) + bf_lo(v2) + bf_lo(v3);
        ay += bf_hi(v0) + bf_hi(v1) + bf_hi(v2) + bf_hi(v3);
    }
    for (; i < end; ++i) {
        unsigned v0 = ybf[(long long)csr_src[i] * 64 + lane];
        ax += bf_lo(v0); ay += bf_hi(v0);
    }
    float inv = (end > beg) ? 1.0f / (float)(end - beg) : 0.f;
    float2* hp = reinterpret_cast<float2*>(h + (long long)node * 128 + lane * 2);
    float2 hv = *hp;
    hv.x += ax * inv;
    hv.y += ay * inv;
    *hp = hv;
}

// ---------------------------------------------------------------------------
// BN stats: sums[c] = sum_r h[r][c], sums[128+c] = sum_r h[r][c]^2
__global__ void bn_stats_kernel(const float* __restrict__ h, float* __restrict__ sums) {
    int c = threadIdx.x & 127;
    int r0 = blockIdx.x * 2 + (threadIdx.x >> 7);
    int stride = gridDim.x * 2;
    float s = 0.f, sq = 0.f;
    for (int r = r0; r < N_NODES; r += stride) {
        float v = h[(long long)r * 128 + c];
        s += v;
        sq += v * v;
    }
    atomicAdd(&sums[c], s);
    atomicAdd(&sums[128 + c], sq);
}

// scale/shift: ss[c] = gamma*rsqrt(var+eps); ss[128+c] = beta - mu*scale
__global__ void bn_finalize_kernel(const float* __restrict__ sums,
                                   const float* __restrict__ gamma,
                                   const float* __restrict__ beta,
                                   float* __restrict__ ss) {
    int c = threadIdx.x;
    float mu  = sums[c] * (1.0f / N_NODES);
    float var = sums[128 + c] * (1.0f / N_NODES) - mu * mu;
    float sc = gamma[c] * rsqrtf(var + BN_EPS);
    ss[c] = sc;
    ss[128 + c] = beta[c] - mu * sc;
}

// ---------------------------------------------------------------------------
// conv2 aggregate: z[n] = bf16( mean_{s in N(n)} t2l[s] + t2r[n] )  (64 ch)
__global__ __launch_bounds__(256) void agg_mean_add_64(
    const int* __restrict__ off, const int* __restrict__ csr_src,
    const unsigned short* __restrict__ t2l, const unsigned short* __restrict__ t2r,
    unsigned short* __restrict__ z) {
    int node = blockIdx.x * 4 + (threadIdx.x >> 6);
    if (node >= N_NODES) return;
    int lane = threadIdx.x & 63;
    int beg = off[node], end = off[node + 1];
    float a = 0.f;
    int i = beg;
    for (; i + 3 < end; i += 4) {
        int s0 = csr_src[i];
        int s1 = csr_src[i + 1];
        int s2 = csr_src[i + 2];
        int s3 = csr_src[i + 3];
        a += bf1(t2l[(long long)s0 * 64 + lane]) + bf1(t2l[(long long)s1 * 64 + lane])
           + bf1(t2l[(long long)s2 * 64 + lane]) + bf1(t2l[(long long)s3 * 64 + lane]);
    }
    for (; i < end; ++i) a += bf1(t2l[(long long)csr_src[i] * 64 + lane]);
    float inv = (end > beg) ? 1.0f / (float)(end - beg) : 0.f;
    float res = bf1(t2r[(long long)node * 64 + lane]) + a * inv;
    z[(long long)node * 64 + lane] = f2bf(res);
}

// ---------------------------------------------------------------------------
// out[l] = dot(z[src_l], z[dst_l]) over 64 bf16 channels; 16 lanes per label
__global__ void edge_dot_kernel(const int* __restrict__ eli,
                                const unsigned short* __restrict__ z,
                                float* __restrict__ out) {
    long long gid = (long long)blockIdx.x * blockDim.x + threadIdx.x;
    int l = (int)(gid >> 4);
    int lane = (int)(gid & 15);
    if (l >= N_LABEL) return;
    int s = eli[l];
    int d = eli[N_LABEL + l];
    uint2 av = *reinterpret_cast<const uint2*>(z + (long long)s * 64 + lane * 4);
    uint2 bv = *reinterpret_cast<const uint2*>(z + (long long)d * 64 + lane * 4);
    float p = bf_lo(av.x) * bf_lo(bv.x) + bf_hi(av.x) * bf_hi(bv.x)
            + bf_lo(av.y) * bf_lo(bv.y) + bf_hi(av.y) * bf_hi(bv.y);
    p += __shfl_down(p, 8, 16);
    p += __shfl_down(p, 4, 16);
    p += __shfl_down(p, 2, 16);
    p += __shfl_down(p, 1, 16);
    if (lane == 0) out[l] = p;
}

// ---------------------------------------------------------------------------
extern "C" void kernel_launch(void* const* d_in, const int* in_sizes, int n_in,
                              void* d_out, int out_size, void* d_ws, size_t ws_size,
                              hipStream_t stream) {
    const float* x     = (const float*)d_in[0];
    const int*   ei    = (const int*)d_in[1];   // [2, 800000]: row0 src, row1 dst
    const int*   eli   = (const int*)d_in[2];   // [2, 200000]
    const float* W1l   = (const float*)d_in[3];
    const float* W1r   = (const float*)d_in[4];
    const float* b1    = (const float*)d_in[5];
    const float* gamma = (const float*)d_in[6];
    const float* beta  = (const float*)d_in[7];
    const float* W2l   = (const float*)d_in[8];
    const float* W2r   = (const float*)d_in[9];
    const float* b2    = (const float*)d_in[10];
    float* out = (float*)d_out;

    const int* src  = ei;
    const int* dstv = ei + N_EDGES;

    // workspace layout (ints first, then bf16/f32 regions; 16B-aligned)
    int* ideg  = (int*)d_ws;             // 50432 (zero-padded to NCHUNK*256)
    int* ioff  = ideg + 50432;           // 50056
    int* ibsum = ioff + 50056;           // 256
    int* iboff = ibsum + 256;            // 256
    int* icsr  = iboff + 256;            // 800000
    unsigned short* y1  = (unsigned short*)(icsr + 800000);  // 6.4M bf16
    float*          h   = (float*)(y1 + 6400000);            // 6.4M f32
    unsigned short* t2l = (unsigned short*)(h + 6400000);    // 3.2M bf16
    unsigned short* t2r = t2l + 3200000;                     // 3.2M bf16
    unsigned short* z   = t2r + 3200000;                     // 3.2M bf16
    float* sums = (float*)(z + 3200000);                     // 256
    float* ss   = sums + 256;                                // 256
    short* Bp1  = (short*)(ss + 256);                        // 32768 bf16 (128x256)
    short* Bp2  = Bp1 + 32768;                               // 16384 bf16 (128x128)
    // rank aliases y1's space: rank is consumed by scatter_kernel, which
    // completes (stream order) before mfma_gemm<0> writes y1.
    int* irank = (int*)y1;               // 800000 ints (3.2 MB < 12.8 MB)

    hipMemsetAsync(ideg, 0, 50432 * sizeof(int), stream);
    hipMemsetAsync(sums, 0, 256 * sizeof(float), stream);

    // ---- weight prep (pack [Wl|Wr] into bf16 MFMA fragment order) ----
    prep_B<<<(128 * 256 + 255) / 256, 256, 0, stream>>>(W1l, W1r, Bp1, 256);
    prep_B<<<(128 * 128 + 255) / 256, 256, 0, stream>>>(W2l, W2r, Bp2, 128);

    // ---- CSR build ----
    hist_kernel<<<(N_EDGES + 255) / 256, 256, 0, stream>>>(dstv, ideg, irank);
    chunk_sum_kernel<<<NCHUNK, 256, 0, stream>>>(ideg, ibsum);
    scan_bsum_kernel<<<1, 256, 0, stream>>>(ibsum, iboff);
    scan_final_kernel<<<NCHUNK, 256, 0, stream>>>(ideg, iboff, ioff);
    scatter_kernel<<<(N_EDGES + 255) / 256, 256, 0, stream>>>(src, dstv, ioff, irank, icsr);

    const int GEMM_GRID = (N_NODES + 63) / 64;   // 782

    // ---- conv1: [y1|h] = bf16mfma(x @ [W1l|W1r]), h gets +b1 ----
    mfma_gemm<0><<<GEMM_GRID, 512, 0, stream>>>(x, Bp1, b1, ss, y1, h, nullptr);
    agg_mean_add_128<<<(N_NODES + 3) / 4, 256, 0, stream>>>(
        ioff, icsr, (const unsigned*)y1, h);

    // ---- batchnorm stats (apply is fused into gemm2 A-load) ----
    bn_stats_kernel<<<500, 256, 0, stream>>>(h, sums);
    bn_finalize_kernel<<<1, 128, 0, stream>>>(sums, gamma, beta, ss);

    // ---- conv2: [t2l|t2r] = bf16mfma(relu(bn(h)) @ [W2l|W2r]), t2r gets +b2 ----
    mfma_gemm<1><<<GEMM_GRID, 512, 0, stream>>>(h, Bp2, b2, ss, t2l, nullptr, t2r);
    agg_mean_add_64<<<(N_NODES + 3) / 4, 256, 0, stream>>>(ioff, icsr, t2l, t2r, z);

    // ---- edge dot readout ----
    edge_dot_kernel<<<((long long)N_LABEL * 16 + 255) / 256, 256, 0, stream>>>(eli, z, out);
}

// Round 9
// 247.808 us; speedup vs baseline: 1.4024x; 1.4024x over previous
//
#include <hip/hip_runtime.h>

constexpr int N_NODES = 50000;
constexpr int IN_C    = 128;
constexpr int HID_C   = 128;
constexpr int OUT_C   = 64;
constexpr int N_EDGES = 800000;
constexpr int N_LABEL = 200000;
constexpr float BN_EPS = 1e-5f;
constexpr int NCHUNK  = (N_NODES + 256) / 256 + 1;   // 196 chunks cover 50176 >= 50001

typedef __attribute__((ext_vector_type(8))) short bf16x8;
typedef __attribute__((ext_vector_type(4))) float f32x4;

// ---- bf16 helpers (plain ushort storage) ----------------------------------
__device__ __forceinline__ float bf_lo(unsigned v) {
    union { unsigned u; float f; } t; t.u = v << 16; return t.f;
}
__device__ __forceinline__ float bf_hi(unsigned v) {
    union { unsigned u; float f; } t; t.u = v & 0xffff0000u; return t.f;
}
__device__ __forceinline__ float bf1(unsigned short u) {
    union { unsigned u; float f; } t; t.u = ((unsigned)u) << 16; return t.f;
}
__device__ __forceinline__ unsigned short f2bf(float f) {
    union { float f; unsigned u; } t; t.f = f;
    unsigned r = t.u + 0x7fffu + ((t.u >> 16) & 1u);   // round-nearest-even
    return (unsigned short)(r >> 16);
}

// ---------------------------------------------------------------------------
// CSR build step 1: histogram of dst; also record each edge's rank within its
// destination node (atomicAdd return value) -> scatter needs no atomics.
__global__ void hist_kernel(const int* __restrict__ dst, int* __restrict__ deg,
                            int* __restrict__ rank) {
    int e = blockIdx.x * blockDim.x + threadIdx.x;
    if (e < N_EDGES) rank[e] = atomicAdd(&deg[dst[e]], 1);
}

// CSR build step 2a: per-chunk sums (deg is zero-padded past N_NODES)
__global__ void chunk_sum_kernel(const int* __restrict__ deg, int* __restrict__ bsum) {
    int i = blockIdx.x * 256 + threadIdx.x;
    int v = deg[i];
    #pragma unroll
    for (int o = 32; o > 0; o >>= 1) v += __shfl_down(v, o, 64);
    __shared__ int ws[4];
    if ((threadIdx.x & 63) == 0) ws[threadIdx.x >> 6] = v;
    __syncthreads();
    if (threadIdx.x == 0) bsum[blockIdx.x] = ws[0] + ws[1] + ws[2] + ws[3];
}

// CSR build step 2b: exclusive scan of the chunk sums (single tiny block)
__global__ void scan_bsum_kernel(const int* __restrict__ bsum, int* __restrict__ boff) {
    __shared__ int t[256];
    int tid = threadIdx.x;
    t[tid] = (tid < NCHUNK) ? bsum[tid] : 0;
    __syncthreads();
    for (int o = 1; o < 256; o <<= 1) {
        int v = t[tid];
        int add = (tid >= o) ? t[tid - o] : 0;
        __syncthreads();
        t[tid] = v + add;
        __syncthreads();
    }
    boff[tid] = (tid == 0) ? 0 : t[tid - 1];
}

// CSR build step 2c: per-chunk exclusive scan + chunk offset -> off
__global__ void scan_final_kernel(const int* __restrict__ deg, const int* __restrict__ boff,
                                  int* __restrict__ off) {
    __shared__ int t[256];
    int tid = threadIdx.x;
    int i = blockIdx.x * 256 + tid;
    int d = deg[i];
    t[tid] = d;
    __syncthreads();
    for (int o = 1; o < 256; o <<= 1) {
        int v = t[tid];
        int add = (tid >= o) ? t[tid - o] : 0;
        __syncthreads();
        t[tid] = v + add;
        __syncthreads();
    }
    int excl = boff[blockIdx.x] + t[tid] - d;
    if (i <= N_NODES) off[i] = excl;       // off[N_NODES] == N_EDGES (deg pad = 0)
}

// CSR build step 3: place src ids (atomic-free: pos = off[dst] + rank)
__global__ void scatter_kernel(const int* __restrict__ src, const int* __restrict__ dst,
                               const int* __restrict__ off, const int* __restrict__ rank,
                               int* __restrict__ csr_src) {
    int e = blockIdx.x * blockDim.x + threadIdx.x;
    if (e < N_EDGES) csr_src[off[dst[e]] + rank[e]] = src[e];
}

// ---------------------------------------------------------------------------
// prep_B: pack [Wl | Wr] (f32, row-major [128][HALF] each) into bf16 fragment
// order for mfma_f32_16x16x32_bf16 B-operand:
//   Bp[((nt*4 + kt)*64 + l)*8 + j] = B[kt*32 + (l>>4)*8 + j][nt*16 + (l&15)]
__global__ void prep_B(const float* __restrict__ Wl, const float* __restrict__ Wr,
                       short* __restrict__ Bp, int C) {
    int f = blockIdx.x * 256 + threadIdx.x;
    if (f >= 128 * C) return;
    int HALF = C >> 1;
    int j = f & 7;
    int l = (f >> 3) & 63;
    int ktnt = f >> 9;
    int kt = ktnt & 3, nt = ktnt >> 2;
    int n = nt * 16 + (l & 15);
    int k = kt * 32 + ((l >> 4) << 3) + j;
    float v = (n < HALF) ? Wl[k * HALF + n] : Wr[k * HALF + (n - HALF)];
    Bp[f] = (short)f2bf(v);
}

// ---------------------------------------------------------------------------
// MFMA GEMM (R6 structure + pre-packed B):
//   256 threads = 4 waves; block covers 64 rows; each wave computes
//   16 rows x C cols (all NT tiles, full unroll -> compiler pipelines the
//   64 ds_read_b128 against MFMAs; R7/R8's unroll-1 exposed load latency).
//   B staged to LDS as a pure 16B/lane memcpy (no conversion VALU, no bank
//   conflicts -- removes R6's 2.4M SQ_LDS_BANK_CONFLICT + 24% VALUBusy).
//   MODE 0 (conv1): A = x (f32), C=256; cols 0..127 -> y1 (bf16),
//                   cols 128..255 -> h = . + b1 (f32)
//   MODE 1 (conv2): A = relu(h*ss0 + ss1) (fused BN), C=128;
//                   cols 0..63 -> t2l (bf16); cols 64..127 -> t2r = . + b2 (bf16)
// Fragment layouts (v_mfma_f32_16x16x32_bf16), verified m89/m91:
//   A: lane l, elem j <- A[m0 + (l&15)][kt*32 + (l>>4)*8 + j]
//   B: lane l, elem j <- B[kt*32 + (l>>4)*8 + j][nt*16 + (l&15)]  (packed order)
//   D: lane l, reg  j -> D[m0 + (l>>4)*4 + j][nt*16 + (l&15)]
template <int MODE>
__global__ __launch_bounds__(256) void mfma_gemm(
    const float* __restrict__ A, const short* __restrict__ Bp,
    const float* __restrict__ bias, const float* __restrict__ ss,
    unsigned short* __restrict__ outL,
    float* __restrict__ outHf, unsigned short* __restrict__ outHb)
{
    constexpr int C    = (MODE == 0) ? 256 : 128;
    constexpr int NT   = C / 16;
    constexpr int HALF = C / 2;
    constexpr int CHUNKS = 128 * C / 8;     // float4 chunks: 4096 / 2048

    __shared__ short sB[128 * C];           // 64 KB (MODE0) / 32 KB (MODE1)

    // ---- stage pre-packed B: straight 16B-per-lane memcpy ----
    {
        const float4* bp4 = reinterpret_cast<const float4*>(Bp);
        float4* sb4 = reinterpret_cast<float4*>(sB);
        #pragma unroll
        for (int i = 0; i < CHUNKS / 256; ++i)
            sb4[i * 256 + threadIdx.x] = bp4[i * 256 + threadIdx.x];
    }

    int tid  = threadIdx.x;
    int wid  = tid >> 6, lane = tid & 63;
    int m0   = blockIdx.x * 64 + wid * 16;
    int row  = m0 + (lane & 15);
    int rowc = (row < N_NODES) ? row : (N_NODES - 1);
    const float* ap = A + (long long)rowc * 128;
    int kbase = (lane >> 4) * 8;

    // ---- A fragments (f32 -> bf16, optional fused BN+ReLU) ----
    bf16x8 a[4];
    #pragma unroll
    for (int kt = 0; kt < 4; ++kt) {
        int k0 = kt * 32 + kbase;
        float4 u0 = *reinterpret_cast<const float4*>(ap + k0);
        float4 u1 = *reinterpret_cast<const float4*>(ap + k0 + 4);
        float v[8] = {u0.x, u0.y, u0.z, u0.w, u1.x, u1.y, u1.z, u1.w};
        if (MODE == 1) {
            float4 s0 = *reinterpret_cast<const float4*>(ss + k0);
            float4 s1 = *reinterpret_cast<const float4*>(ss + k0 + 4);
            float4 t0 = *reinterpret_cast<const float4*>(ss + 128 + k0);
            float4 t1 = *reinterpret_cast<const float4*>(ss + 128 + k0 + 4);
            float sc[8] = {s0.x, s0.y, s0.z, s0.w, s1.x, s1.y, s1.z, s1.w};
            float sh[8] = {t0.x, t0.y, t0.z, t0.w, t1.x, t1.y, t1.z, t1.w};
            #pragma unroll
            for (int j = 0; j < 8; ++j) v[j] = fmaxf(v[j] * sc[j] + sh[j], 0.f);
        }
        #pragma unroll
        for (int j = 0; j < 8; ++j) a[kt][j] = (short)f2bf(v[j]);
    }

    __syncthreads();

    // ---- MFMA main loop: FULL unroll (compiler pipelines ds_reads) ----
    f32x4 acc[NT] = {};
    #pragma unroll
    for (int kt = 0; kt < 4; ++kt) {
        #pragma unroll
        for (int nt = 0; nt < NT; ++nt) {
            bf16x8 b = *reinterpret_cast<const bf16x8*>(
                sB + ((((nt << 2) + kt) * 64 + lane) << 3));
            acc[nt] = __builtin_amdgcn_mfma_f32_16x16x32_bf16(a[kt], b, acc[nt], 0, 0, 0);
        }
    }

    // ---- epilogue ----
    int r0 = m0 + ((lane >> 4) << 2);
    int nl = lane & 15;
    #pragma unroll
    for (int nt = 0; nt < NT; ++nt) {
        int col = nt * 16 + nl;
        float bb = (col >= HALF) ? bias[col - HALF] : 0.f;
        #pragma unroll
        for (int j = 0; j < 4; ++j) {
            int r = r0 + j;
            if (r >= N_NODES) continue;
            float vv = acc[nt][j];
            if (MODE == 0) {
                if (col < HALF) outL[(long long)r * 128 + col] = f2bf(vv);
                else            outHf[(long long)r * 128 + (col - HALF)] = vv + bb;
            } else {
                if (col < HALF) outL[(long long)r * 64 + col] = f2bf(vv);
                else            outHb[(long long)r * 64 + (col - HALF)] = f2bf(vv + bb);
            }
        }
    }
}

// ---------------------------------------------------------------------------
// conv1 aggregate: h[n] += mean_{s in N(n)} y1[s]  (y1 bf16-packed, 128 ch)
__global__ __launch_bounds__(256) void agg_mean_add_128(
    const int* __restrict__ off, const int* __restrict__ csr_src,
    const unsigned* __restrict__ ybf, float* __restrict__ h) {
    int node = blockIdx.x * 4 + (threadIdx.x >> 6);
    if (node >= N_NODES) return;
    int lane = threadIdx.x & 63;
    int beg = off[node], end = off[node + 1];
    float ax = 0.f, ay = 0.f;
    int i = beg;
    for (; i + 3 < end; i += 4) {
        int s0 = csr_src[i];
        int s1 = csr_src[i + 1];
        int s2 = csr_src[i + 2];
        int s3 = csr_src[i + 3];
        unsigned v0 = ybf[(long long)s0 * 64 + lane];
        unsigned v1 = ybf[(long long)s1 * 64 + lane];
        unsigned v2 = ybf[(long long)s2 * 64 + lane];
        unsigned v3 = ybf[(long long)s3 * 64 + lane];
        ax += bf_lo(v0) + bf_lo(v1) + bf_lo(v2) + bf_lo(v3);
        ay += bf_hi(v0) + bf_hi(v1) + bf_hi(v2) + bf_hi(v3);
    }
    for (; i < end; ++i) {
        unsigned v0 = ybf[(long long)csr_src[i] * 64 + lane];
        ax += bf_lo(v0); ay += bf_hi(v0);
    }
    float inv = (end > beg) ? 1.0f / (float)(end - beg) : 0.f;
    float2* hp = reinterpret_cast<float2*>(h + (long long)node * 128 + lane * 2);
    float2 hv = *hp;
    hv.x += ax * inv;
    hv.y += ay * inv;
    *hp = hv;
}

// ---------------------------------------------------------------------------
// BN stats: sums[c] = sum_r h[r][c], sums[128+c] = sum_r h[r][c]^2
__global__ void bn_stats_kernel(const float* __restrict__ h, float* __restrict__ sums) {
    int c = threadIdx.x & 127;
    int r0 = blockIdx.x * 2 + (threadIdx.x >> 7);
    int stride = gridDim.x * 2;
    float s = 0.f, sq = 0.f;
    for (int r = r0; r < N_NODES; r += stride) {
        float v = h[(long long)r * 128 + c];
        s += v;
        sq += v * v;
    }
    atomicAdd(&sums[c], s);
    atomicAdd(&sums[128 + c], sq);
}

// scale/shift: ss[c] = gamma*rsqrt(var+eps); ss[128+c] = beta - mu*scale
__global__ void bn_finalize_kernel(const float* __restrict__ sums,
                                   const float* __restrict__ gamma,
                                   const float* __restrict__ beta,
                                   float* __restrict__ ss) {
    int c = threadIdx.x;
    float mu  = sums[c] * (1.0f / N_NODES);
    float var = sums[128 + c] * (1.0f / N_NODES) - mu * mu;
    float sc = gamma[c] * rsqrtf(var + BN_EPS);
    ss[c] = sc;
    ss[128 + c] = beta[c] - mu * sc;
}

// ---------------------------------------------------------------------------
// conv2 aggregate: z[n] = bf16( mean_{s in N(n)} t2l[s] + t2r[n] )  (64 ch)
__global__ __launch_bounds__(256) void agg_mean_add_64(
    const int* __restrict__ off, const int* __restrict__ csr_src,
    const unsigned short* __restrict__ t2l, const unsigned short* __restrict__ t2r,
    unsigned short* __restrict__ z) {
    int node = blockIdx.x * 4 + (threadIdx.x >> 6);
    if (node >= N_NODES) return;
    int lane = threadIdx.x & 63;
    int beg = off[node], end = off[node + 1];
    float a = 0.f;
    int i = beg;
    for (; i + 3 < end; i += 4) {
        int s0 = csr_src[i];
        int s1 = csr_src[i + 1];
        int s2 = csr_src[i + 2];
        int s3 = csr_src[i + 3];
        a += bf1(t2l[(long long)s0 * 64 + lane]) + bf1(t2l[(long long)s1 * 64 + lane])
           + bf1(t2l[(long long)s2 * 64 + lane]) + bf1(t2l[(long long)s3 * 64 + lane]);
    }
    for (; i < end; ++i) a += bf1(t2l[(long long)csr_src[i] * 64 + lane]);
    float inv = (end > beg) ? 1.0f / (float)(end - beg) : 0.f;
    float res = bf1(t2r[(long long)node * 64 + lane]) + a * inv;
    z[(long long)node * 64 + lane] = f2bf(res);
}

// ---------------------------------------------------------------------------
// out[l] = dot(z[src_l], z[dst_l]) over 64 bf16 channels; 16 lanes per label
__global__ void edge_dot_kernel(const int* __restrict__ eli,
                                const unsigned short* __restrict__ z,
                                float* __restrict__ out) {
    long long gid = (long long)blockIdx.x * blockDim.x + threadIdx.x;
    int l = (int)(gid >> 4);
    int lane = (int)(gid & 15);
    if (l >= N_LABEL) return;
    int s = eli[l];
    int d = eli[N_LABEL + l];
    uint2 av = *reinterpret_cast<const uint2*>(z + (long long)s * 64 + lane * 4);
    uint2 bv = *reinterpret_cast<const uint2*>(z + (long long)d * 64 + lane * 4);
    float p = bf_lo(av.x) * bf_lo(bv.x) + bf_hi(av.x) * bf_hi(bv.x)
            + bf_lo(av.y) * bf_lo(bv.y) + bf_hi(av.y) * bf_hi(bv.y);
    p += __shfl_down(p, 8, 16);
    p += __shfl_down(p, 4, 16);
    p += __shfl_down(p, 2, 16);
    p += __shfl_down(p, 1, 16);
    if (lane == 0) out[l] = p;
}

// ---------------------------------------------------------------------------
extern "C" void kernel_launch(void* const* d_in, const int* in_sizes, int n_in,
                              void* d_out, int out_size, void* d_ws, size_t ws_size,
                              hipStream_t stream) {
    const float* x     = (const float*)d_in[0];
    const int*   ei    = (const int*)d_in[1];   // [2, 800000]: row0 src, row1 dst
    const int*   eli   = (const int*)d_in[2];   // [2, 200000]
    const float* W1l   = (const float*)d_in[3];
    const float* W1r   = (const float*)d_in[4];
    const float* b1    = (const float*)d_in[5];
    const float* gamma = (const float*)d_in[6];
    const float* beta  = (const float*)d_in[7];
    const float* W2l   = (const float*)d_in[8];
    const float* W2r   = (const float*)d_in[9];
    const float* b2    = (const float*)d_in[10];
    float* out = (float*)d_out;

    const int* src  = ei;
    const int* dstv = ei + N_EDGES;

    // workspace layout (ints first, then bf16/f32 regions; 16B-aligned)
    int* ideg  = (int*)d_ws;             // 50432 (zero-padded to NCHUNK*256)
    int* ioff  = ideg + 50432;           // 50056
    int* ibsum = ioff + 50056;           // 256
    int* iboff = ibsum + 256;            // 256
    int* icsr  = iboff + 256;            // 800000
    unsigned short* y1  = (unsigned short*)(icsr + 800000);  // 6.4M bf16
    float*          h   = (float*)(y1 + 6400000);            // 6.4M f32
    unsigned short* t2l = (unsigned short*)(h + 6400000);    // 3.2M bf16
    unsigned short* t2r = t2l + 3200000;                     // 3.2M bf16
    unsigned short* z   = t2r + 3200000;                     // 3.2M bf16
    float* sums = (float*)(z + 3200000);                     // 256
    float* ss   = sums + 256;                                // 256
    short* Bp1  = (short*)(ss + 256);                        // 32768 bf16 (128x256)
    short* Bp2  = Bp1 + 32768;                               // 16384 bf16 (128x128)
    // rank aliases y1's space: rank is consumed by scatter_kernel, which
    // completes (stream order) before mfma_gemm<0> writes y1.
    int* irank = (int*)y1;               // 800000 ints (3.2 MB < 12.8 MB)

    hipMemsetAsync(ideg, 0, 50432 * sizeof(int), stream);
    hipMemsetAsync(sums, 0, 256 * sizeof(float), stream);

    // ---- weight prep (pack [Wl|Wr] into bf16 MFMA fragment order) ----
    prep_B<<<(128 * 256 + 255) / 256, 256, 0, stream>>>(W1l, W1r, Bp1, 256);
    prep_B<<<(128 * 128 + 255) / 256, 256, 0, stream>>>(W2l, W2r, Bp2, 128);

    // ---- CSR build ----
    hist_kernel<<<(N_EDGES + 255) / 256, 256, 0, stream>>>(dstv, ideg, irank);
    chunk_sum_kernel<<<NCHUNK, 256, 0, stream>>>(ideg, ibsum);
    scan_bsum_kernel<<<1, 256, 0, stream>>>(ibsum, iboff);
    scan_final_kernel<<<NCHUNK, 256, 0, stream>>>(ideg, iboff, ioff);
    scatter_kernel<<<(N_EDGES + 255) / 256, 256, 0, stream>>>(src, dstv, ioff, irank, icsr);

    const int GEMM_GRID = (N_NODES + 63) / 64;   // 782

    // ---- conv1: [y1|h] = bf16mfma(x @ [W1l|W1r]), h gets +b1 ----
    mfma_gemm<0><<<GEMM_GRID, 256, 0, stream>>>(x, Bp1, b1, ss, y1, h, nullptr);
    agg_mean_add_128<<<(N_NODES + 3) / 4, 256, 0, stream>>>(
        ioff, icsr, (const unsigned*)y1, h);

    // ---- batchnorm stats (apply is fused into gemm2 A-load) ----
    bn_stats_kernel<<<500, 256, 0, stream>>>(h, sums);
    bn_finalize_kernel<<<1, 128, 0, stream>>>(sums, gamma, beta, ss);

    // ---- conv2: [t2l|t2r] = bf16mfma(relu(bn(h)) @ [W2l|W2r]), t2r gets +b2 ----
    mfma_gemm<1><<<GEMM_GRID, 256, 0, stream>>>(h, Bp2, b2, ss, t2l, nullptr, t2r);
    agg_mean_add_64<<<(N_NODES + 3) / 4, 256, 0, stream>>>(ioff, icsr, t2l, t2r, z);

    // ---- edge dot readout ----
    edge_dot_kernel<<<((long long)N_LABEL * 16 + 255) / 256, 256, 0, stream>>>(eli, z, out);
}